// Round 8
// baseline (232.984 us; speedup 1.0000x reference)
//
#include <hip/hip_runtime.h>
#include <hip/hip_bf16.h>
#include <cstdint>
#include <math.h>

#define BB 256
#define CC 64
#define TT 4000
#define NHID 64
#define NOUT 64
#define NMLP (NOUT*(CC+1))  // 4160
#define TCH 256             // t per k_apply block

// ---------------- K1: fused per-channel log-variance + MLP hypernetwork ----------------
// grid 256 (one block per sample b), block 1024. 16 threads per channel row.
// Produces wsB[b][o] (fp32) and wtg[b][c][o] (bf16, transposed for k_apply LDS reads).
__global__ __launch_bounds__(1024) void k_feat(const float* __restrict__ x,
                                               const float* __restrict__ W1,
                                               const float* __restrict__ b1,
                                               const float* __restrict__ W2,
                                               const float* __restrict__ b2,
                                               __hip_bfloat16* __restrict__ wtg,
                                               float* __restrict__ wsB) {
    int b   = blockIdx.x;
    int tid = threadIdx.x;
    int c   = tid >> 4;      // 0..63
    int sub = tid & 15;      // 0..15

    const float4* row = (const float4*)(x + (size_t)b * (CC * TT) + (size_t)c * TT);
    float s = 0.f, ss = 0.f;
    #pragma unroll 4
    for (int i = sub; i < TT / 4; i += 16) {   // 1000 float4 per row / 16 threads
        float4 v = row[i];
        s  += v.x + v.y + v.z + v.w;
        ss += v.x * v.x + v.y * v.y + v.z * v.z + v.w * v.w;
    }
    #pragma unroll
    for (int off = 8; off > 0; off >>= 1) {
        s  += __shfl_xor(s, off);
        ss += __shfl_xor(ss, off);
    }

    __shared__ float fs[CC];
    __shared__ float hs[NHID];
    if (sub == 0) {
        float var = (ss - s * s / (float)TT) / (float)(TT - 1);
        float f = logf(var);
        if (isinf(f) && f < 0.f) f = 0.f;   // jnp.where(isneginf, 0, .)
        fs[c] = f;
    }
    __syncthreads();

    if (tid < NHID) {
        float v = b1[tid];
        #pragma unroll 8
        for (int k = 0; k < CC; ++k) v = fmaf(fs[k], W1[k * NHID + tid], v);
        hs[tid] = v > 0.f ? v : 0.f;
    }
    __syncthreads();

    for (int j = tid; j < NMLP; j += 1024) {
        float v = b2[j];
        #pragma unroll 8
        for (int k = 0; k < NHID; ++k) v = fmaf(hs[k], W2[k * NMLP + j], v);
        if (j < NOUT) {
            wsB[b * NOUT + j] = v;
        } else {
            int kk = j - NOUT;
            int o = kk >> 6, c2 = kk & 63;               // mlp_out[64+o*64+c] = W[o][c]
            wtg[(size_t)b * 4096 + c2 * 64 + o] = __float2bfloat16(v);  // [c][o] bf16
        }
    }
}

// ---------------- K2: out[b,o,t] = sum_c W[o,c]*x[b,c,t] + bias[o] ----------------
// grid (16, 256), block 256. 8x8 register patch per thread (og=tid&7, tg=tid>>3).
// x fp32 [64][256] + W bf16 [c][o] in LDS (72.25 KB -> 2 blocks/CU).
// T14 double-buffer: load half0->regs, ds_write, load half1->regs, sync,
// compute c0..31 (hides half1 HBM latency), ds_write half1 (disjoint region),
// sync, compute c32..63. Staging latency off the critical path.
__global__ __launch_bounds__(256, 2) void k_apply(const float* __restrict__ x,
                                                  const __hip_bfloat16* __restrict__ wtg,
                                                  const float* __restrict__ wsB,
                                                  float* __restrict__ out) {
    int b   = (BB - 1) - blockIdx.y;    // reversed: reuse x tail from k_feat in L3
    int tb  = blockIdx.x * TCH;
    int tid = threadIdx.x;

    __shared__ float          xs[CC][TCH];   // 64 KB
    __shared__ unsigned short wt[CC][64];    // 8 KB, [c][o] bf16
    __shared__ float          bl[64];

    const float* xb = x + (size_t)b * (CC * TT) + tb;
    int maxf4 = ((TT - tb) >> 2) - 1;        // 63 normally, 39 on tail chunk

    // ---- issue half-0 x loads + W/bias loads into registers ----
    float4 st0[8];
    #pragma unroll
    for (int r = 0; r < 8; ++r) {
        int idx = r * 256 + tid;
        int c   = idx >> 6;                  // 0..31
        int f4  = idx & 63;
        int f4c = f4 < maxf4 ? f4 : maxf4;
        st0[r] = *(const float4*)(xb + (size_t)c * TT + f4c * 4);
    }
    const uint4* wg = (const uint4*)(wtg + (size_t)b * 4096);
    uint4 wr0 = wg[tid], wr1 = wg[256 + tid];
    float4 breg = {0.f, 0.f, 0.f, 0.f};
    if (tid < 16) breg = ((const float4*)(wsB + b * 64))[tid];

    // ---- write half 0 + W/bias to LDS ----
    #pragma unroll
    for (int r = 0; r < 8; ++r) {
        int idx = r * 256 + tid;
        *(float4*)&xs[idx >> 6][(idx & 63) * 4] = st0[r];
    }
    ((uint4*)wt)[tid] = wr0;
    ((uint4*)wt)[256 + tid] = wr1;
    if (tid < 16) ((float4*)bl)[tid] = breg;

    // ---- issue half-1 x loads (in flight during sync + half-0 compute) ----
    float4 st1[8];
    #pragma unroll
    for (int r = 0; r < 8; ++r) {
        int idx = r * 256 + tid;
        int c   = 32 + (idx >> 6);           // 32..63
        int f4  = idx & 63;
        int f4c = f4 < maxf4 ? f4 : maxf4;
        st1[r] = *(const float4*)(xb + (size_t)c * TT + f4c * 4);
    }
    __syncthreads();

    int og = tid & 7;        // o-block: o = og*8 + oo
    int tg = tid >> 3;       // t-block: t = tb + tg*8 + j

    float acc[8][8];
    {
        float4 b0 = *(const float4*)&bl[og * 8];
        float4 b1v = *(const float4*)&bl[og * 8 + 4];
        float bv[8] = {b0.x, b0.y, b0.z, b0.w, b1v.x, b1v.y, b1v.z, b1v.w};
        #pragma unroll
        for (int oo = 0; oo < 8; ++oo)
            #pragma unroll
            for (int j = 0; j < 8; ++j) acc[oo][j] = bv[oo];
    }

    // ---- compute half 0 (c = 0..31) ----
    #pragma unroll 2
    for (int c = 0; c < 32; ++c) {
        uint4  wraw = *(const uint4*)&wt[c][og * 8];
        float4 xa   = *(const float4*)&xs[c][tg * 8];
        float4 xc   = *(const float4*)&xs[c][tg * 8 + 4];
        float w[8];
        w[0] = __uint_as_float(wraw.x << 16);
        w[1] = __uint_as_float(wraw.x & 0xFFFF0000u);
        w[2] = __uint_as_float(wraw.y << 16);
        w[3] = __uint_as_float(wraw.y & 0xFFFF0000u);
        w[4] = __uint_as_float(wraw.z << 16);
        w[5] = __uint_as_float(wraw.z & 0xFFFF0000u);
        w[6] = __uint_as_float(wraw.w << 16);
        w[7] = __uint_as_float(wraw.w & 0xFFFF0000u);
        float xv[8] = {xa.x, xa.y, xa.z, xa.w, xc.x, xc.y, xc.z, xc.w};
        #pragma unroll
        for (int oo = 0; oo < 8; ++oo)
            #pragma unroll
            for (int j = 0; j < 8; ++j)
                acc[oo][j] = fmaf(w[oo], xv[j], acc[oo][j]);
    }

    // ---- write half 1 (disjoint LDS region: no barrier needed before) ----
    #pragma unroll
    for (int r = 0; r < 8; ++r) {
        int idx = r * 256 + tid;
        *(float4*)&xs[32 + (idx >> 6)][(idx & 63) * 4] = st1[r];
    }
    __syncthreads();

    // ---- compute half 1 (c = 32..63) ----
    #pragma unroll 2
    for (int c = 32; c < 64; ++c) {
        uint4  wraw = *(const uint4*)&wt[c][og * 8];
        float4 xa   = *(const float4*)&xs[c][tg * 8];
        float4 xc   = *(const float4*)&xs[c][tg * 8 + 4];
        float w[8];
        w[0] = __uint_as_float(wraw.x << 16);
        w[1] = __uint_as_float(wraw.x & 0xFFFF0000u);
        w[2] = __uint_as_float(wraw.y << 16);
        w[3] = __uint_as_float(wraw.y & 0xFFFF0000u);
        w[4] = __uint_as_float(wraw.z << 16);
        w[5] = __uint_as_float(wraw.z & 0xFFFF0000u);
        w[6] = __uint_as_float(wraw.w << 16);
        w[7] = __uint_as_float(wraw.w & 0xFFFF0000u);
        float xv[8] = {xa.x, xa.y, xa.z, xa.w, xc.x, xc.y, xc.z, xc.w};
        #pragma unroll
        for (int oo = 0; oo < 8; ++oo)
            #pragma unroll
            for (int j = 0; j < 8; ++j)
                acc[oo][j] = fmaf(w[oo], xv[j], acc[oo][j]);
    }

    int t0 = tb + tg * 8;
    if (t0 < TT) {                            // tail chunk: tg>=20 masked
        float* op = out + (size_t)b * (NOUT * TT) + (size_t)(og * 8) * TT + t0;
        #pragma unroll
        for (int oo = 0; oo < 8; ++oo) {
            *(float4*)(op + (size_t)oo * TT)     = {acc[oo][0], acc[oo][1], acc[oo][2], acc[oo][3]};
            *(float4*)(op + (size_t)oo * TT + 4) = {acc[oo][4], acc[oo][5], acc[oo][6], acc[oo][7]};
        }
    }
}

extern "C" void kernel_launch(void* const* d_in, const int* in_sizes, int n_in,
                              void* d_out, int out_size, void* d_ws, size_t ws_size,
                              hipStream_t stream) {
    const float* x  = (const float*)d_in[0];
    const float* W1 = (const float*)d_in[1];
    const float* b1 = (const float*)d_in[2];
    const float* W2 = (const float*)d_in[3];
    const float* b2 = (const float*)d_in[4];
    float* out = (float*)d_out;
    float* ws  = (float*)d_ws;

    float*           wsB = ws;                              // 256*64 fp32
    __hip_bfloat16*  wtg = (__hip_bfloat16*)(ws + 16384);   // 256*4096 bf16 (2 MB)

    k_feat<<<256, 1024, 0, stream>>>(x, W1, b1, W2, b2, wtg, wsB);
    k_apply<<<dim3(16, 256), 256, 0, stream>>>(x, wtg, wsB, out);
}

// Round 9
// 198.891 us; speedup vs baseline: 1.1714x; 1.1714x over previous
//
#include <hip/hip_runtime.h>
#include <hip/hip_bf16.h>
#include <cstdint>
#include <math.h>

#define BB 256
#define CC 64
#define TT 4000
#define NHID 64
#define NOUT 64
#define NMLP (NOUT*(CC+1))  // 4160
#define TCH 256             // t per k_apply block

// async global->LDS, 16B per lane, wave-uniform LDS base + lane*16
#define GLDS(g, l) __builtin_amdgcn_global_load_lds(                         \
    (const __attribute__((address_space(1))) void*)(g),                      \
    (__attribute__((address_space(3))) void*)(l), 16, 0, 0)

// ---------------- K1: fused per-channel log-variance + MLP hypernetwork ----------------
// grid 256 (one block per sample b), block 1024. 16 threads per channel row.
// Produces wsB[b][o] (fp32) and wtg[b][c][o] (bf16, transposed for k_apply LDS reads).
__global__ __launch_bounds__(1024) void k_feat(const float* __restrict__ x,
                                               const float* __restrict__ W1,
                                               const float* __restrict__ b1,
                                               const float* __restrict__ W2,
                                               const float* __restrict__ b2,
                                               __hip_bfloat16* __restrict__ wtg,
                                               float* __restrict__ wsB) {
    int b   = blockIdx.x;
    int tid = threadIdx.x;
    int c   = tid >> 4;      // 0..63
    int sub = tid & 15;      // 0..15

    const float4* row = (const float4*)(x + (size_t)b * (CC * TT) + (size_t)c * TT);
    float s = 0.f, ss = 0.f;
    #pragma unroll 4
    for (int i = sub; i < TT / 4; i += 16) {   // 1000 float4 per row / 16 threads
        float4 v = row[i];
        s  += v.x + v.y + v.z + v.w;
        ss += v.x * v.x + v.y * v.y + v.z * v.z + v.w * v.w;
    }
    #pragma unroll
    for (int off = 8; off > 0; off >>= 1) {
        s  += __shfl_xor(s, off);
        ss += __shfl_xor(ss, off);
    }

    __shared__ float fs[CC];
    __shared__ float hs[NHID];
    if (sub == 0) {
        float var = (ss - s * s / (float)TT) / (float)(TT - 1);
        float f = logf(var);
        if (isinf(f) && f < 0.f) f = 0.f;   // jnp.where(isneginf, 0, .)
        fs[c] = f;
    }
    __syncthreads();

    if (tid < NHID) {
        float v = b1[tid];
        #pragma unroll 8
        for (int k = 0; k < CC; ++k) v = fmaf(fs[k], W1[k * NHID + tid], v);
        hs[tid] = v > 0.f ? v : 0.f;
    }
    __syncthreads();

    for (int j = tid; j < NMLP; j += 1024) {
        float v = b2[j];
        #pragma unroll 8
        for (int k = 0; k < NHID; ++k) v = fmaf(hs[k], W2[k * NMLP + j], v);
        if (j < NOUT) {
            wsB[b * NOUT + j] = v;
        } else {
            int kk = j - NOUT;
            int o = kk >> 6, c2 = kk & 63;               // mlp_out[64+o*64+c] = W[o][c]
            wtg[(size_t)b * 4096 + c2 * 64 + o] = __float2bfloat16(v);  // [c][o] bf16
        }
    }
}

// ---------------- K2: out[b,o,t] = sum_c W[o,c]*x[b,c,t] + bias[o] ----------------
// grid (16, 256), block 256. 8x8 register patch per thread (og=tid&7, tg=tid>>3).
// x fp32 [64][256] + W bf16 [c][o] in LDS (72 KB -> 2 blocks/CU).
// Staging via global_load_lds (no staging regs -> no spill, R8 lesson) with
// counted vmcnt + RAW s_barrier (T3/T4): half-1 loads stay in flight across
// the first barrier and land under half-0's compute.
__global__ __launch_bounds__(256, 2) void k_apply(const float* __restrict__ x,
                                                  const __hip_bfloat16* __restrict__ wtg,
                                                  const float* __restrict__ wsB,
                                                  float* __restrict__ out) {
    int b    = (BB - 1) - blockIdx.y;   // reversed: reuse x tail from k_feat in L3
    int tb   = blockIdx.x * TCH;
    int tid  = threadIdx.x;
    int wave = tid >> 6, lane = tid & 63;
    int og   = tid & 7;                 // o-block: o = og*8 + oo
    int tg   = tid >> 3;                // t-block: t = tb + tg*8 + j

    __shared__ float          xs[CC][TCH];   // 64 KB
    __shared__ unsigned short wt[CC][64];    // 8 KB, [c][o] bf16

    // ---- bias straight to regs, issued FIRST (oldest vmcnt entries) ----
    const float* bb = wsB + b * 64 + og * 8;     // 8 distinct 32B segs/wave: coalesced
    float4 brg0 = *(const float4*)bb;
    float4 brg1 = *(const float4*)(bb + 4);

    const float* xb = x + (size_t)b * (CC * TT) + tb;
    int maxf4 = ((TT - tb) >> 2) - 1;            // binds only on tail chunk (39)
    int f4c   = lane < maxf4 ? lane : maxf4;     // per-lane clamped global offset
    const float* xsrc = xb + f4c * 4;

    // ---- issue half-0 x rows (8 glds/wave, 1 KB LDS row each) ----
    #pragma unroll
    for (int r = 0; r < 8; ++r) {
        int c = wave * 8 + r;                    // rows 0..31
        GLDS(xsrc + (size_t)c * TT, &xs[c][0]);
    }
    // ---- issue W (2 glds/wave; wtg[b] layout matches wt exactly) ----
    const char* wsrc = (const char*)(wtg + (size_t)b * 4096) + wave * 2048 + lane * 16;
    char*       wdst = (char*)&wt[0][0] + wave * 2048;
    GLDS(wsrc, wdst);
    GLDS(wsrc + 1024, wdst + 1024);
    // ---- issue half-1 x rows (stay in flight across the barrier) ----
    #pragma unroll
    for (int r = 0; r < 8; ++r) {
        int c = 32 + wave * 8 + r;               // rows 32..63
        GLDS(xsrc + (size_t)c * TT, &xs[c][0]);
    }

    // wait bias+half0+W (leave 8 = half-1 outstanding), then sync waves
    asm volatile("s_waitcnt vmcnt(8)" ::: "memory");
    __builtin_amdgcn_sched_barrier(0);
    __builtin_amdgcn_s_barrier();

    float acc[8][8];
    {
        float bv[8] = {brg0.x, brg0.y, brg0.z, brg0.w, brg1.x, brg1.y, brg1.z, brg1.w};
        #pragma unroll
        for (int oo = 0; oo < 8; ++oo)
            #pragma unroll
            for (int j = 0; j < 8; ++j) acc[oo][j] = bv[oo];
    }

    // ---- compute half 0 (c = 0..31); half-1 loads landing underneath ----
    #pragma unroll 2
    for (int c = 0; c < 32; ++c) {
        uint4  wraw = *(const uint4*)&wt[c][og * 8];
        float4 xa   = *(const float4*)&xs[c][tg * 8];
        float4 xc   = *(const float4*)&xs[c][tg * 8 + 4];
        float w[8];
        w[0] = __uint_as_float(wraw.x << 16);
        w[1] = __uint_as_float(wraw.x & 0xFFFF0000u);
        w[2] = __uint_as_float(wraw.y << 16);
        w[3] = __uint_as_float(wraw.y & 0xFFFF0000u);
        w[4] = __uint_as_float(wraw.z << 16);
        w[5] = __uint_as_float(wraw.z & 0xFFFF0000u);
        w[6] = __uint_as_float(wraw.w << 16);
        w[7] = __uint_as_float(wraw.w & 0xFFFF0000u);
        float xv[8] = {xa.x, xa.y, xa.z, xa.w, xc.x, xc.y, xc.z, xc.w};
        #pragma unroll
        for (int oo = 0; oo < 8; ++oo)
            #pragma unroll
            for (int j = 0; j < 8; ++j)
                acc[oo][j] = fmaf(w[oo], xv[j], acc[oo][j]);
    }

    // half-1 landed? drain and sync, then compute
    asm volatile("s_waitcnt vmcnt(0)" ::: "memory");
    __builtin_amdgcn_sched_barrier(0);
    __builtin_amdgcn_s_barrier();

    // ---- compute half 1 (c = 32..63) ----
    #pragma unroll 2
    for (int c = 32; c < 64; ++c) {
        uint4  wraw = *(const uint4*)&wt[c][og * 8];
        float4 xa   = *(const float4*)&xs[c][tg * 8];
        float4 xc   = *(const float4*)&xs[c][tg * 8 + 4];
        float w[8];
        w[0] = __uint_as_float(wraw.x << 16);
        w[1] = __uint_as_float(wraw.x & 0xFFFF0000u);
        w[2] = __uint_as_float(wraw.y << 16);
        w[3] = __uint_as_float(wraw.y & 0xFFFF0000u);
        w[4] = __uint_as_float(wraw.z << 16);
        w[5] = __uint_as_float(wraw.z & 0xFFFF0000u);
        w[6] = __uint_as_float(wraw.w << 16);
        w[7] = __uint_as_float(wraw.w & 0xFFFF0000u);
        float xv[8] = {xa.x, xa.y, xa.z, xa.w, xc.x, xc.y, xc.z, xc.w};
        #pragma unroll
        for (int oo = 0; oo < 8; ++oo)
            #pragma unroll
            for (int j = 0; j < 8; ++j)
                acc[oo][j] = fmaf(w[oo], xv[j], acc[oo][j]);
    }

    int t0 = tb + tg * 8;
    if (t0 < TT) {                            // tail chunk: tg>=20 masked
        float* op = out + (size_t)b * (NOUT * TT) + (size_t)(og * 8) * TT + t0;
        #pragma unroll
        for (int oo = 0; oo < 8; ++oo) {
            *(float4*)(op + (size_t)oo * TT)     = {acc[oo][0], acc[oo][1], acc[oo][2], acc[oo][3]};
            *(float4*)(op + (size_t)oo * TT + 4) = {acc[oo][4], acc[oo][5], acc[oo][6], acc[oo][7]};
        }
    }
}

extern "C" void kernel_launch(void* const* d_in, const int* in_sizes, int n_in,
                              void* d_out, int out_size, void* d_ws, size_t ws_size,
                              hipStream_t stream) {
    const float* x  = (const float*)d_in[0];
    const float* W1 = (const float*)d_in[1];
    const float* b1 = (const float*)d_in[2];
    const float* W2 = (const float*)d_in[3];
    const float* b2 = (const float*)d_in[4];
    float* out = (float*)d_out;
    float* ws  = (float*)d_ws;

    float*           wsB = ws;                              // 256*64 fp32
    __hip_bfloat16*  wtg = (__hip_bfloat16*)(ws + 16384);   // 256*4096 bf16 (2 MB)

    k_feat<<<256, 1024, 0, stream>>>(x, W1, b1, W2, b2, wtg, wsB);
    k_apply<<<dim3(16, 256), 256, 0, stream>>>(x, wtg, wsB, out);
}

// Round 10
// 194.671 us; speedup vs baseline: 1.1968x; 1.0217x over previous
//
#include <hip/hip_runtime.h>
#include <hip/hip_bf16.h>
#include <cstdint>
#include <math.h>

#define BB 256
#define CC 64
#define TT 4000
#define NHID 64
#define NOUT 64
#define NMLP (NOUT*(CC+1))  // 4160
#define TCH 128             // t per k_apply block (32 KB x-tile -> 4 blocks/CU)

// async global->LDS, 16B per lane, wave-uniform LDS base + lane*16
#define GLDS(g, l) __builtin_amdgcn_global_load_lds(                         \
    (const __attribute__((address_space(1))) void*)(g),                      \
    (__attribute__((address_space(3))) void*)(l), 16, 0, 0)

// ---------------- K1: fused per-channel log-variance + MLP hypernetwork ----------------
// grid 256 (one block per sample b), block 1024. 16 threads per channel row.
// Produces wsB[b][o] (fp32) and wtg[b][c][o] (bf16, transposed for k_apply LDS reads).
__global__ __launch_bounds__(1024) void k_feat(const float* __restrict__ x,
                                               const float* __restrict__ W1,
                                               const float* __restrict__ b1,
                                               const float* __restrict__ W2,
                                               const float* __restrict__ b2,
                                               __hip_bfloat16* __restrict__ wtg,
                                               float* __restrict__ wsB) {
    int b   = blockIdx.x;
    int tid = threadIdx.x;
    int c   = tid >> 4;      // 0..63
    int sub = tid & 15;      // 0..15

    const float4* row = (const float4*)(x + (size_t)b * (CC * TT) + (size_t)c * TT);
    float s = 0.f, ss = 0.f;
    #pragma unroll 4
    for (int i = sub; i < TT / 4; i += 16) {   // 1000 float4 per row / 16 threads
        float4 v = row[i];
        s  += v.x + v.y + v.z + v.w;
        ss += v.x * v.x + v.y * v.y + v.z * v.z + v.w * v.w;
    }
    #pragma unroll
    for (int off = 8; off > 0; off >>= 1) {
        s  += __shfl_xor(s, off);
        ss += __shfl_xor(ss, off);
    }

    __shared__ float fs[CC];
    __shared__ float hs[NHID];
    if (sub == 0) {
        float var = (ss - s * s / (float)TT) / (float)(TT - 1);
        float f = logf(var);
        if (isinf(f) && f < 0.f) f = 0.f;   // jnp.where(isneginf, 0, .)
        fs[c] = f;
    }
    __syncthreads();

    if (tid < NHID) {
        float v = b1[tid];
        #pragma unroll 8
        for (int k = 0; k < CC; ++k) v = fmaf(fs[k], W1[k * NHID + tid], v);
        hs[tid] = v > 0.f ? v : 0.f;
    }
    __syncthreads();

    for (int j = tid; j < NMLP; j += 1024) {
        float v = b2[j];
        #pragma unroll 8
        for (int k = 0; k < NHID; ++k) v = fmaf(hs[k], W2[k * NMLP + j], v);
        if (j < NOUT) {
            wsB[b * NOUT + j] = v;
        } else {
            int kk = j - NOUT;
            int o = kk >> 6, c2 = kk & 63;               // mlp_out[64+o*64+c] = W[o][c]
            wtg[(size_t)b * 4096 + c2 * 64 + o] = __float2bfloat16(v);  // [c][o] bf16
        }
    }
}

// ---------------- K2: out[b,o,t] = sum_c W[o,c]*x[b,c,t] + bias[o] ----------------
// grid (32, 256), block 256. 8o x 4t register patch per thread (og=tid&7, tg=tid>>3).
// LDS = x fp32 [64][128] (32 KB) + W bf16 [c][o] (8 KB) = 40960 B exactly
// -> 4 blocks/CU (full 160 KB pool) -> 4 waves/SIMD, phase-decorrelated.
// Staging via global_load_lds (no staging regs), counted vmcnt + raw s_barrier:
// half-1 x rows stay in flight across the first barrier, land under half-0 compute.
__global__ __launch_bounds__(256) void k_apply(const float* __restrict__ x,
                                               const __hip_bfloat16* __restrict__ wtg,
                                               const float* __restrict__ wsB,
                                               float* __restrict__ out) {
    int b    = (BB - 1) - blockIdx.y;   // reversed: reuse x tail from k_feat in L3
    int tb   = blockIdx.x * TCH;        // 0..3968
    int tid  = threadIdx.x;
    int wave = tid >> 6, lane = tid & 63;
    int og   = tid & 7;                 // o-block: o = og*8 + oo
    int tg   = tid >> 3;                // t-block: t = tb + tg*4 + j, tg in [0,32)

    __shared__ float          xs[CC][TCH];   // 32 KB
    __shared__ unsigned short wt[CC][64];    // 8 KB, [c][o] bf16

    // ---- bias straight to regs, issued FIRST (oldest vmcnt entries) ----
    const float* bb = wsB + b * 64 + og * 8;
    float4 brg0 = *(const float4*)bb;
    float4 brg1 = *(const float4*)(bb + 4);

    const float* xb = x + (size_t)b * (CC * TT) + tb;
    int maxf4 = ((TT - tb) >> 2) - 1;        // 31 normally; 7 on tail chunk
    int myf4  = lane & 31;                   // 32 float4 per 128-t row
    if (myf4 > maxf4) myf4 = maxf4;          // clamp GLOBAL side only
    int rowoff = lane >> 5;                  // lanes 32..63 -> second row
    const float* xsrc = xb + (size_t)rowoff * TT + myf4 * 4;

    // ---- issue half-0 x rows (4 glds/wave, each covers 2 rows = 1 KB) ----
    #pragma unroll
    for (int r = 0; r < 4; ++r) {
        int c = wave * 8 + r * 2;            // rows 0..31
        GLDS(xsrc + (size_t)c * TT, &xs[c][0]);
    }
    // ---- issue W (2 glds/wave; wtg[b] layout matches wt exactly) ----
    const char* wsrc = (const char*)(wtg + (size_t)b * 4096) + wave * 2048 + lane * 16;
    char*       wdst = (char*)&wt[0][0] + wave * 2048;
    GLDS(wsrc, wdst);
    GLDS(wsrc + 1024, wdst + 1024);
    // ---- issue half-1 x rows (stay in flight across the barrier) ----
    #pragma unroll
    for (int r = 0; r < 4; ++r) {
        int c = 32 + wave * 8 + r * 2;       // rows 32..63
        GLDS(xsrc + (size_t)c * TT, &xs[c][0]);
    }

    // wait bias+half0+W (leave 4 = half-1 outstanding), then sync waves
    asm volatile("s_waitcnt vmcnt(4)" ::: "memory");
    __builtin_amdgcn_sched_barrier(0);
    __builtin_amdgcn_s_barrier();

    float acc[8][4];
    {
        float bv[8] = {brg0.x, brg0.y, brg0.z, brg0.w, brg1.x, brg1.y, brg1.z, brg1.w};
        #pragma unroll
        for (int oo = 0; oo < 8; ++oo)
            #pragma unroll
            for (int j = 0; j < 4; ++j) acc[oo][j] = bv[oo];
    }

    // ---- compute half 0 (c = 0..31); half-1 loads landing underneath ----
    #pragma unroll 4
    for (int c = 0; c < 32; ++c) {
        uint4  wraw = *(const uint4*)&wt[c][og * 8];
        float4 xa   = *(const float4*)&xs[c][tg * 4];
        float w[8];
        w[0] = __uint_as_float(wraw.x << 16);
        w[1] = __uint_as_float(wraw.x & 0xFFFF0000u);
        w[2] = __uint_as_float(wraw.y << 16);
        w[3] = __uint_as_float(wraw.y & 0xFFFF0000u);
        w[4] = __uint_as_float(wraw.z << 16);
        w[5] = __uint_as_float(wraw.z & 0xFFFF0000u);
        w[6] = __uint_as_float(wraw.w << 16);
        w[7] = __uint_as_float(wraw.w & 0xFFFF0000u);
        float xv[4] = {xa.x, xa.y, xa.z, xa.w};
        #pragma unroll
        for (int oo = 0; oo < 8; ++oo)
            #pragma unroll
            for (int j = 0; j < 4; ++j)
                acc[oo][j] = fmaf(w[oo], xv[j], acc[oo][j]);
    }

    // half-1 landed? drain and sync, then compute
    asm volatile("s_waitcnt vmcnt(0)" ::: "memory");
    __builtin_amdgcn_sched_barrier(0);
    __builtin_amdgcn_s_barrier();

    // ---- compute half 1 (c = 32..63) ----
    #pragma unroll 4
    for (int c = 32; c < 64; ++c) {
        uint4  wraw = *(const uint4*)&wt[c][og * 8];
        float4 xa   = *(const float4*)&xs[c][tg * 4];
        float w[8];
        w[0] = __uint_as_float(wraw.x << 16);
        w[1] = __uint_as_float(wraw.x & 0xFFFF0000u);
        w[2] = __uint_as_float(wraw.y << 16);
        w[3] = __uint_as_float(wraw.y & 0xFFFF0000u);
        w[4] = __uint_as_float(wraw.z << 16);
        w[5] = __uint_as_float(wraw.z & 0xFFFF0000u);
        w[6] = __uint_as_float(wraw.w << 16);
        w[7] = __uint_as_float(wraw.w & 0xFFFF0000u);
        float xv[4] = {xa.x, xa.y, xa.z, xa.w};
        #pragma unroll
        for (int oo = 0; oo < 8; ++oo)
            #pragma unroll
            for (int j = 0; j < 4; ++j)
                acc[oo][j] = fmaf(w[oo], xv[j], acc[oo][j]);
    }

    int t0 = tb + tg * 4;
    if (t0 < TT) {                            // tail chunk: tg>=8 masked
        float* op = out + (size_t)b * (NOUT * TT) + (size_t)(og * 8) * TT + t0;
        #pragma unroll
        for (int oo = 0; oo < 8; ++oo)
            *(float4*)(op + (size_t)oo * TT) = {acc[oo][0], acc[oo][1], acc[oo][2], acc[oo][3]};
    }
}

extern "C" void kernel_launch(void* const* d_in, const int* in_sizes, int n_in,
                              void* d_out, int out_size, void* d_ws, size_t ws_size,
                              hipStream_t stream) {
    const float* x  = (const float*)d_in[0];
    const float* W1 = (const float*)d_in[1];
    const float* b1 = (const float*)d_in[2];
    const float* W2 = (const float*)d_in[3];
    const float* b2 = (const float*)d_in[4];
    float* out = (float*)d_out;
    float* ws  = (float*)d_ws;

    float*           wsB = ws;                              // 256*64 fp32
    __hip_bfloat16*  wtg = (__hip_bfloat16*)(ws + 16384);   // 256*4096 bf16 (2 MB)

    k_feat<<<256, 1024, 0, stream>>>(x, W1, b1, W2, b2, wtg, wsB);
    k_apply<<<dim3(32, 256), 256, 0, stream>>>(x, wtg, wsB, out);
}

// Round 11
// 178.999 us; speedup vs baseline: 1.3016x; 1.0876x over previous
//
#include <hip/hip_runtime.h>
#include <hip/hip_bf16.h>
#include <cstdint>
#include <math.h>

#define BB 256
#define CC 64
#define TT 4000
#define NHID 64
#define NOUT 64
#define NMLP (NOUT*(CC+1))  // 4160
#define TCH 128             // t per k_apply block

typedef __attribute__((ext_vector_type(8))) short short8v;  // 8 bf16 = 4 VGPR
typedef __attribute__((ext_vector_type(4))) float f32x4;    // MFMA C/D frag

// ---------------- K1: fused per-channel log-variance + MLP hypernetwork ----------------
// grid 256 (one block per sample b), block 1024. 16 threads per channel row.
// Produces wsB[b][o] (fp32) and wtg[b][o][c] (bf16, NATURAL layout for A-fragments).
__global__ __launch_bounds__(1024) void k_feat(const float* __restrict__ x,
                                               const float* __restrict__ W1,
                                               const float* __restrict__ b1,
                                               const float* __restrict__ W2,
                                               const float* __restrict__ b2,
                                               __hip_bfloat16* __restrict__ wtg,
                                               float* __restrict__ wsB) {
    int b   = blockIdx.x;
    int tid = threadIdx.x;
    int c   = tid >> 4;      // 0..63
    int sub = tid & 15;      // 0..15

    const float4* row = (const float4*)(x + (size_t)b * (CC * TT) + (size_t)c * TT);
    float s = 0.f, ss = 0.f;
    #pragma unroll 4
    for (int i = sub; i < TT / 4; i += 16) {   // 1000 float4 per row / 16 threads
        float4 v = row[i];
        s  += v.x + v.y + v.z + v.w;
        ss += v.x * v.x + v.y * v.y + v.z * v.z + v.w * v.w;
    }
    #pragma unroll
    for (int off = 8; off > 0; off >>= 1) {
        s  += __shfl_xor(s, off);
        ss += __shfl_xor(ss, off);
    }

    __shared__ float fs[CC];
    __shared__ float hs[NHID];
    if (sub == 0) {
        float var = (ss - s * s / (float)TT) / (float)(TT - 1);
        float f = logf(var);
        if (isinf(f) && f < 0.f) f = 0.f;   // jnp.where(isneginf, 0, .)
        fs[c] = f;
    }
    __syncthreads();

    if (tid < NHID) {
        float v = b1[tid];
        #pragma unroll 8
        for (int k = 0; k < CC; ++k) v = fmaf(fs[k], W1[k * NHID + tid], v);
        hs[tid] = v > 0.f ? v : 0.f;
    }
    __syncthreads();

    for (int j = tid; j < NMLP; j += 1024) {
        float v = b2[j];
        #pragma unroll 8
        for (int k = 0; k < NHID; ++k) v = fmaf(hs[k], W2[k * NMLP + j], v);
        if (j < NOUT) {
            wsB[b * NOUT + j] = v;
        } else {
            // mlp_out[64 + o*64 + c] = W[o][c]  -> natural [o][c] bf16
            wtg[(size_t)b * 4096 + (j - NOUT)] = __float2bfloat16(v);
        }
    }
}

// ---------------- K2 (MFMA): out[b,o,t] = sum_c W[o,c]*x[b,c,t] + bias[o] ----------------
// grid (32, 256), block 256 (4 waves). Per block: b x 128-t chunk.
// Stage x fp32 -> bf16 hi/lo split -> LDS [t][c] (XOR-swizzled, 2x16KB).
// Wave w owns t in [w*32, w*32+32): 2 t-tiles. A = W (bf16, global/L2-hot),
// B = x hi/lo from LDS, D = 16x16 tiles; 32 mfma_f32_16x16x32_bf16 per wave.
// A row=l&15, k=(l>>4)*8+j; B col=l&15, same k; D col=l&15, row=(l>>4)*4+r (m89).
__global__ __launch_bounds__(256, 4) void k_apply(const float* __restrict__ x,
                                                  const __hip_bfloat16* __restrict__ wtg,
                                                  const float* __restrict__ wsB,
                                                  float* __restrict__ out) {
    int b   = (BB - 1) - blockIdx.y;    // reversed: reuse x tail from k_feat in L3
    int tb  = blockIdx.x * TCH;
    int tid = threadIdx.x;
    int l   = tid & 63, w = tid >> 6;

    __shared__ unsigned short xt[2][TCH * CC];  // [hi/lo][t*64 + c], 16 KB each

    // ---- staging: thread owns c-octet (cslot) x t-quad (f4) ----
    int cslot = tid & 7;                 // c = cslot*8 + p
    int f4    = tid >> 3;                // t-quad 0..31
    int maxf4 = ((TT - tb) >> 2) - 1;    // 7 on tail chunk only
    int f4c   = f4 <= maxf4 ? f4 : maxf4;
    const float* xb = x + (size_t)b * (CC * TT) + tb + f4c * 4;

    float4 xr[8];
    #pragma unroll
    for (int p = 0; p < 8; ++p)
        xr[p] = *(const float4*)(xb + (size_t)(cslot * 8 + p) * TT);

    #pragma unroll
    for (int j = 0; j < 4; ++j) {
        int t = f4 * 4 + j;
        short8v hv, lv;
        #pragma unroll
        for (int p = 0; p < 8; ++p) {
            float v = (&xr[p].x)[j];
            __hip_bfloat16 h = __float2bfloat16(v);                 // RTN hi
            unsigned short hu = *(unsigned short*)&h;
            float hf = __uint_as_float((unsigned)hu << 16);
            __hip_bfloat16 lo = __float2bfloat16(v - hf);           // RTN residual
            hv[p] = (short)hu;
            lv[p] = (short)*(unsigned short*)&lo;
        }
        int byteoff = t * 128 + ((cslot * 16) ^ ((t & 7) << 4));    // XOR swizzle
        *(short8v*)((char*)&xt[0][0] + byteoff) = hv;
        *(short8v*)((char*)&xt[1][0] + byteoff) = lv;
    }
    __syncthreads();

    // ---- A-fragments (W) straight from global (L2-hot; 16B/lane, aligned) ----
    const __hip_bfloat16* wb = wtg + (size_t)b * 4096;
    short8v af[4][2];
    #pragma unroll
    for (int mi = 0; mi < 4; ++mi)
        #pragma unroll
        for (int kc = 0; kc < 2; ++kc)
            af[mi][kc] = *(const short8v*)(wb + (mi * 16 + (l & 15)) * 64
                                              + kc * 32 + (l >> 4) * 8);

    // ---- acc init from bias: D row o = (l>>4)*4 + r ----
    f32x4 acc[4][2];
    #pragma unroll
    for (int mi = 0; mi < 4; ++mi) {
        float4 bv = *(const float4*)(wsB + b * 64 + mi * 16 + (l >> 4) * 4);
        #pragma unroll
        for (int ti = 0; ti < 2; ++ti) {
            acc[mi][ti][0] = bv.x; acc[mi][ti][1] = bv.y;
            acc[mi][ti][2] = bv.z; acc[mi][ti][3] = bv.w;
        }
    }

    // ---- MFMA main: per t-tile read 4 B-frags, run 16 MFMAs ----
    #pragma unroll
    for (int ti = 0; ti < 2; ++ti) {
        int tl = w * 32 + ti * 16 + (l & 15);         // t row in LDS
        int rowbase = tl * 128;
        int sw = (tl & 7) << 4;
        short8v bf[2][2];                             // [kc][hi/lo]
        #pragma unroll
        for (int kc = 0; kc < 2; ++kc) {
            int boff = rowbase + ((kc * 64 + (l >> 4) * 16) ^ sw);
            bf[kc][0] = *(const short8v*)((const char*)&xt[0][0] + boff);
            bf[kc][1] = *(const short8v*)((const char*)&xt[1][0] + boff);
        }
        #pragma unroll
        for (int mi = 0; mi < 4; ++mi)
            #pragma unroll
            for (int kc = 0; kc < 2; ++kc) {
                acc[mi][ti] = __builtin_amdgcn_mfma_f32_16x16x32_bf16(
                                  af[mi][kc], bf[kc][0], acc[mi][ti], 0, 0, 0);
                acc[mi][ti] = __builtin_amdgcn_mfma_f32_16x16x32_bf16(
                                  af[mi][kc], bf[kc][1], acc[mi][ti], 0, 0, 0);
            }
    }

    // ---- stores: lane l -> o = mi*16+(l>>4)*4+r, t = tb+w*32+ti*16+(l&15) ----
    #pragma unroll
    for (int mi = 0; mi < 4; ++mi)
        #pragma unroll
        for (int ti = 0; ti < 2; ++ti) {
            int t = tb + w * 32 + ti * 16 + (l & 15);
            if (t < TT) {
                float* op = out + (size_t)b * (NOUT * TT)
                                + (size_t)(mi * 16 + (l >> 4) * 4) * TT + t;
                #pragma unroll
                for (int r = 0; r < 4; ++r)
                    op[(size_t)r * TT] = acc[mi][ti][r];
            }
        }
}

extern "C" void kernel_launch(void* const* d_in, const int* in_sizes, int n_in,
                              void* d_out, int out_size, void* d_ws, size_t ws_size,
                              hipStream_t stream) {
    const float* x  = (const float*)d_in[0];
    const float* W1 = (const float*)d_in[1];
    const float* b1 = (const float*)d_in[2];
    const float* W2 = (const float*)d_in[3];
    const float* b2 = (const float*)d_in[4];
    float* out = (float*)d_out;
    float* ws  = (float*)d_ws;

    float*           wsB = ws;                              // 256*64 fp32
    __hip_bfloat16*  wtg = (__hip_bfloat16*)(ws + 16384);   // 256*4096 bf16 (2 MB)

    k_feat<<<256, 1024, 0, stream>>>(x, W1, b1, W2, b2, wtg, wsB);
    k_apply<<<dim3(32, 256), 256, 0, stream>>>(x, wtg, wsB, out);
}

// Round 12
// 150.307 us; speedup vs baseline: 1.5501x; 1.1909x over previous
//
#include <hip/hip_runtime.h>
#include <hip/hip_bf16.h>
#include <cstdint>
#include <math.h>

#define BB 256
#define CC 64
#define TT 4000
#define NHID 64
#define NOUT 64
#define NMLP (NOUT*(CC+1))  // 4160
#define TCH 128             // t per k_apply block

typedef __attribute__((ext_vector_type(8))) short short8v;  // 8 bf16 = 4 VGPR
typedef __attribute__((ext_vector_type(4))) float f32x4;    // MFMA C/D frag

// ---------------- K1: fused per-channel log-variance + MLP hypernetwork ----------------
// grid 256 (one block per sample b), block 1024. 16 threads per channel row.
// Produces wsB[b][o] (fp32) and wtg[b][o][c] (bf16, NATURAL layout for A-fragments).
__global__ __launch_bounds__(1024) void k_feat(const float* __restrict__ x,
                                               const float* __restrict__ W1,
                                               const float* __restrict__ b1,
                                               const float* __restrict__ W2,
                                               const float* __restrict__ b2,
                                               __hip_bfloat16* __restrict__ wtg,
                                               float* __restrict__ wsB) {
    int b   = blockIdx.x;
    int tid = threadIdx.x;
    int c   = tid >> 4;      // 0..63
    int sub = tid & 15;      // 0..15

    const float4* row = (const float4*)(x + (size_t)b * (CC * TT) + (size_t)c * TT);
    float s = 0.f, ss = 0.f;
    #pragma unroll 4
    for (int i = sub; i < TT / 4; i += 16) {   // 1000 float4 per row / 16 threads
        float4 v = row[i];
        s  += v.x + v.y + v.z + v.w;
        ss += v.x * v.x + v.y * v.y + v.z * v.z + v.w * v.w;
    }
    #pragma unroll
    for (int off = 8; off > 0; off >>= 1) {
        s  += __shfl_xor(s, off);
        ss += __shfl_xor(ss, off);
    }

    __shared__ float fs[CC];
    __shared__ float hs[NHID];
    if (sub == 0) {
        float var = (ss - s * s / (float)TT) / (float)(TT - 1);
        float f = logf(var);
        if (isinf(f) && f < 0.f) f = 0.f;   // jnp.where(isneginf, 0, .)
        fs[c] = f;
    }
    __syncthreads();

    if (tid < NHID) {
        float v = b1[tid];
        #pragma unroll 8
        for (int k = 0; k < CC; ++k) v = fmaf(fs[k], W1[k * NHID + tid], v);
        hs[tid] = v > 0.f ? v : 0.f;
    }
    __syncthreads();

    for (int j = tid; j < NMLP; j += 1024) {
        float v = b2[j];
        #pragma unroll 8
        for (int k = 0; k < NHID; ++k) v = fmaf(hs[k], W2[k * NMLP + j], v);
        if (j < NOUT) {
            wsB[b * NOUT + j] = v;
        } else {
            // mlp_out[64 + o*64 + c] = W[o][c]  -> natural [o][c] bf16
            wtg[(size_t)b * 4096 + (j - NOUT)] = __float2bfloat16(v);
        }
    }
}

// ---------------- K2 (MFMA): out[b,o,t] = sum_c W[o,c]*x[b,c,t] + bias[o] ----------------
// grid (32, 256), block 256 (4 waves). Per block: b x 128-t chunk.
// Stage x fp32 -> bf16 hi/lo split -> LDS [t][c] (XOR-swizzled, 2x16KB).
// 32 mfma_f32_16x16x32_bf16 per wave. Epilogue: LDS transpose (reusing the
// x-buffer) -> full-line f32x4 NON-TEMPORAL stores, so out never allocates
// in L2/L3 and x stays L3-resident for the next pass/replay.
__global__ __launch_bounds__(256, 4) void k_apply(const float* __restrict__ x,
                                                  const __hip_bfloat16* __restrict__ wtg,
                                                  const float* __restrict__ wsB,
                                                  float* __restrict__ out) {
    int b   = (BB - 1) - blockIdx.y;    // reversed: reuse x tail from k_feat in L3
    int tb  = blockIdx.x * TCH;
    int tid = threadIdx.x;
    int l   = tid & 63, w = tid >> 6;

    __shared__ unsigned short xt[2][TCH * CC];  // [hi/lo][t*64 + c], 16 KB each

    // ---- staging: thread owns c-octet (cslot) x t-quad (f4) ----
    int cslot = tid & 7;                 // c = cslot*8 + p
    int f4    = tid >> 3;                // t-quad 0..31
    int maxf4 = ((TT - tb) >> 2) - 1;    // 7 on tail chunk only
    int f4c   = f4 <= maxf4 ? f4 : maxf4;
    const float* xb = x + (size_t)b * (CC * TT) + tb + f4c * 4;

    float4 xr[8];
    #pragma unroll
    for (int p = 0; p < 8; ++p)
        xr[p] = *(const float4*)(xb + (size_t)(cslot * 8 + p) * TT);

    #pragma unroll
    for (int j = 0; j < 4; ++j) {
        int t = f4 * 4 + j;
        short8v hv, lv;
        #pragma unroll
        for (int p = 0; p < 8; ++p) {
            float v = (&xr[p].x)[j];
            __hip_bfloat16 h = __float2bfloat16(v);                 // RTN hi
            unsigned short hu = *(unsigned short*)&h;
            float hf = __uint_as_float((unsigned)hu << 16);
            __hip_bfloat16 lo = __float2bfloat16(v - hf);           // RTN residual
            hv[p] = (short)hu;
            lv[p] = (short)*(unsigned short*)&lo;
        }
        int byteoff = t * 128 + ((cslot * 16) ^ ((t & 7) << 4));    // XOR swizzle
        *(short8v*)((char*)&xt[0][0] + byteoff) = hv;
        *(short8v*)((char*)&xt[1][0] + byteoff) = lv;
    }
    __syncthreads();

    // ---- A-fragments (W) straight from global (L2/L3-hot; 16B/lane, aligned) ----
    const __hip_bfloat16* wb = wtg + (size_t)b * 4096;
    short8v af[4][2];
    #pragma unroll
    for (int mi = 0; mi < 4; ++mi)
        #pragma unroll
        for (int kc = 0; kc < 2; ++kc)
            af[mi][kc] = *(const short8v*)(wb + (mi * 16 + (l & 15)) * 64
                                              + kc * 32 + (l >> 4) * 8);

    // ---- acc init from bias: D row o = (l>>4)*4 + r ----
    f32x4 acc[4][2];
    #pragma unroll
    for (int mi = 0; mi < 4; ++mi) {
        float4 bv = *(const float4*)(wsB + b * 64 + mi * 16 + (l >> 4) * 4);
        #pragma unroll
        for (int ti = 0; ti < 2; ++ti) {
            acc[mi][ti][0] = bv.x; acc[mi][ti][1] = bv.y;
            acc[mi][ti][2] = bv.z; acc[mi][ti][3] = bv.w;
        }
    }

    // ---- MFMA main: per t-tile read 4 B-frags, run 16 MFMAs ----
    #pragma unroll
    for (int ti = 0; ti < 2; ++ti) {
        int tl = w * 32 + ti * 16 + (l & 15);         // t row in LDS
        int rowbase = tl * 128;
        int sw = (tl & 7) << 4;
        short8v bf[2][2];                             // [kc][hi/lo]
        #pragma unroll
        for (int kc = 0; kc < 2; ++kc) {
            int boff = rowbase + ((kc * 64 + (l >> 4) * 16) ^ sw);
            bf[kc][0] = *(const short8v*)((const char*)&xt[0][0] + boff);
            bf[kc][1] = *(const short8v*)((const char*)&xt[1][0] + boff);
        }
        #pragma unroll
        for (int mi = 0; mi < 4; ++mi)
            #pragma unroll
            for (int kc = 0; kc < 2; ++kc) {
                acc[mi][ti] = __builtin_amdgcn_mfma_f32_16x16x32_bf16(
                                  af[mi][kc], bf[kc][0], acc[mi][ti], 0, 0, 0);
                acc[mi][ti] = __builtin_amdgcn_mfma_f32_16x16x32_bf16(
                                  af[mi][kc], bf[kc][1], acc[mi][ti], 0, 0, 0);
            }
    }

    // ---- epilogue: transpose via LDS (reuse xt, 32 KB) then full-line NT stores ----
    __syncthreads();                     // all B-frag reads done; xt reusable
    float* ot = (float*)&xt[0][0];       // [o][t^((o&7)<<2)], 64 x 128 fp32

    #pragma unroll
    for (int mi = 0; mi < 4; ++mi)
        #pragma unroll
        for (int ti = 0; ti < 2; ++ti) {
            int t = w * 32 + ti * 16 + (l & 15);
            #pragma unroll
            for (int r = 0; r < 4; ++r) {
                int o = mi * 16 + (l >> 4) * 4 + r;
                ot[o * 128 + (t ^ ((o & 7) << 2))] = acc[mi][ti][r];  // 2-way (free)
            }
        }
    __syncthreads();

    // read back row-major, store 16B/lane with 8 consecutive lanes per o-row
    // (128B contiguous per row per instr = full line -> NT safe, no amplification)
    int ro = tid >> 3;                   // 0..31 (two o-passes)
    int q0 = tid & 7;                    // quad slot within row
    #pragma unroll
    for (int k2 = 0; k2 < 2; ++k2) {
        int o = ro + k2 * 32;
        int sw = (o & 7) << 2;
        float* op = out + (size_t)b * (NOUT * TT) + (size_t)o * TT + tb;
        #pragma unroll
        for (int kq = 0; kq < 4; ++kq) {
            int t0 = (q0 + kq * 8) * 4;
            if (tb + t0 < TT) {
                f32x4 v = *(const f32x4*)&ot[o * 128 + (t0 ^ sw)];
                __builtin_nontemporal_store(v, (f32x4*)(op + t0));
            }
        }
    }
}

extern "C" void kernel_launch(void* const* d_in, const int* in_sizes, int n_in,
                              void* d_out, int out_size, void* d_ws, size_t ws_size,
                              hipStream_t stream) {
    const float* x  = (const float*)d_in[0];
    const float* W1 = (const float*)d_in[1];
    const float* b1 = (const float*)d_in[2];
    const float* W2 = (const float*)d_in[3];
    const float* b2 = (const float*)d_in[4];
    float* out = (float*)d_out;
    float* ws  = (float*)d_ws;

    float*           wsB = ws;                              // 256*64 fp32
    __hip_bfloat16*  wtg = (__hip_bfloat16*)(ws + 16384);   // 256*4096 bf16 (2 MB)

    k_feat<<<256, 1024, 0, stream>>>(x, W1, b1, W2, b2, wtg, wsB);
    k_apply<<<dim3(32, 256), 256, 0, stream>>>(x, wtg, wsB, out);
}